// Round 7
// baseline (824.845 us; speedup 1.0000x reference)
//
#include <hip/hip_runtime.h>

typedef __attribute__((ext_vector_type(8))) short bh8;
typedef __attribute__((ext_vector_type(4))) short bh4;
typedef __attribute__((ext_vector_type(4))) float f32x4;

__device__ __forceinline__ short f2bf(float f) {
  union { float f; unsigned u; } a; a.f = f;
  unsigned r = a.u + 0x7FFFu + ((a.u >> 16) & 1u);
  return (short)(r >> 16);
}

// async global->LDS DMA, 16B per lane; LDS dest must be wave-uniform base + lane*16
__device__ __forceinline__ void g2l16(const short* g, short* l) {
  __builtin_amdgcn_global_load_lds(
      (const __attribute__((address_space(1))) void*)g,
      (__attribute__((address_space(3))) void*)l, 16, 0, 0);
}

// raw barrier: no vmcnt/lgkmcnt drain (unlike __syncthreads), compiler-fenced
__device__ __forceinline__ void barrier_raw() {
  asm volatile("" ::: "memory");
  __builtin_amdgcn_s_barrier();
  asm volatile("" ::: "memory");
}

// forced LDS read: volatile asm ds_read_b128, compile-time offset immediate.
// addr operand is the low 32 bits of a generic LDS pointer (= segment offset).
__device__ __forceinline__ void dsr(bh8& d, unsigned a, int imm) {
  asm volatile("ds_read_b128 %0, %1 offset:%2" : "=v"(d) : "v"(a), "i"(imm));
}

// ---------------------------------------------------------------------------
// Zero only the 132 halo rows of each padded tensor (q,k,v are contiguous).
// ---------------------------------------------------------------------------
__global__ __launch_bounds__(256) void zero_halo(short* __restrict__ xP) {
  int z = blockIdx.y;  // (tensor*8 + b), buffers contiguous
  short* base = xP + (size_t)z * 1183744;
  int ri = blockIdx.x * 2 + (threadIdx.x >> 7);  // 0..131
  int row;
  if (ri < 34) row = ri;                           // y = 0
  else if (ri < 68) row = 1122 + (ri - 34);        // y = 33
  else { int j = ri - 68; int y = (j >> 1) + 1; int x = (j & 1) ? 33 : 0; row = y * 34 + x; }
  int col = (threadIdx.x & 127) * 8;
  bh8 zv = {0, 0, 0, 0, 0, 0, 0, 0};
  *(bh8*)(base + (size_t)row * 1024 + col) = zv;
}

// ---------------------------------------------------------------------------
// Prep 1: x[b][c][32*32] (f32) -> xP[b][(y+1)*34+(x+1)][c] (bf16), halo=0.
// ---------------------------------------------------------------------------
__global__ __launch_bounds__(256) void transpose3(
    const float* __restrict__ q, const float* __restrict__ k, const float* __restrict__ v,
    short* __restrict__ qP, short* __restrict__ kP, short* __restrict__ vP) {
  int z = blockIdx.z; int tensor = z >> 3, b = z & 7;
  const float* src = tensor == 0 ? q : (tensor == 1 ? k : v);
  short* dst = tensor == 0 ? qP : (tensor == 1 ? kP : vP);
  src += (size_t)b * 1048576; dst += (size_t)b * 1183744;  // 1156*1024
  int row0 = blockIdx.y * 64;  // c
  int col0 = blockIdx.x * 64;  // s
  __shared__ short t[64][72];
  int tid = threadIdx.x;
#pragma unroll
  for (int i = 0; i < 2; ++i) {
    int cid = tid + i * 256;
    int r = cid >> 3, co = (cid & 7) * 8;
    const float* p = src + (size_t)(row0 + r) * 1024 + col0 + co;
    float4 f0 = *(const float4*)(p);
    float4 f1 = *(const float4*)(p + 4);
    t[co + 0][r] = f2bf(f0.x); t[co + 1][r] = f2bf(f0.y);
    t[co + 2][r] = f2bf(f0.z); t[co + 3][r] = f2bf(f0.w);
    t[co + 4][r] = f2bf(f1.x); t[co + 5][r] = f2bf(f1.y);
    t[co + 6][r] = f2bf(f1.z); t[co + 7][r] = f2bf(f1.w);
  }
  __syncthreads();
#pragma unroll
  for (int i = 0; i < 2; ++i) {
    int cid = tid + i * 256;
    int sr = cid >> 3, cc = (cid & 7) * 8;
    bh8 val = *(const bh8*)&t[sr][cc];
    int tok = col0 + sr;
    int pr = ((tok >> 5) + 1) * 34 + (tok & 31) + 1;
    *(bh8*)(dst + (size_t)pr * 1024 + row0 + cc) = val;
  }
}

// ---------------------------------------------------------------------------
// Prep 2: Wp[tap][o][c] (bf16) = W[o][c][tap] (f32).  grid (4096, 3)
// ---------------------------------------------------------------------------
__global__ __launch_bounds__(256) void wperm3(
    const float* __restrict__ Wq, const float* __restrict__ Wk, const float* __restrict__ Wv,
    short* __restrict__ WpQ, short* __restrict__ WpK, short* __restrict__ WpV) {
  int z = blockIdx.y;
  const float* W = z == 0 ? Wq : (z == 1 ? Wk : Wv);
  short* Wp = z == 0 ? WpQ : (z == 1 ? WpK : WpV);
  int idx = blockIdx.x * 256 + threadIdx.x;  // (o,c) flat, 0..1M
  const float* wsrc = W + (size_t)idx * 9;
#pragma unroll
  for (int t = 0; t < 9; ++t) Wp[(size_t)t * 1048576 + idx] = f2bf(wsrc[t]);
}

// ---------------------------------------------------------------------------
// Prep 3: Wo f32 -> bf16 flat.  grid (1024)
// ---------------------------------------------------------------------------
__global__ __launch_bounds__(256) void cvt_bf(const float* __restrict__ src,
                                              short* __restrict__ dst) {
  int idx = (blockIdx.x * 256 + threadIdx.x) * 4;
  float4 f = *(const float4*)(src + idx);
  bh4 o; o[0] = f2bf(f.x); o[1] = f2bf(f.y); o[2] = f2bf(f.z); o[3] = f2bf(f.w);
  *(bh4*)(dst + idx) = o;
}

// ---------------------------------------------------------------------------
// Prep 4: pack mask int32 -> bits. word idx = (b*1024 + t)*32 + (s>>5)
// ---------------------------------------------------------------------------
__global__ __launch_bounds__(256) void mask_pack(const int* __restrict__ m,
                                                 unsigned* __restrict__ mp) {
  int idx = blockIdx.x * 256 + threadIdx.x;
  const int* src = m + (size_t)idx * 32;
  unsigned wv = 0;
#pragma unroll
  for (int j = 0; j < 32; j += 4) {
    int4 a = *(const int4*)(src + j);
    wv |= ((unsigned)(a.x & 1) << j) | ((unsigned)(a.y & 1) << (j + 1)) |
          ((unsigned)(a.z & 1) << (j + 2)) | ((unsigned)(a.w & 1) << (j + 3));
  }
  mp[idx] = wv;
}

// ---------------------------------------------------------------------------
// Fused conv3x3 implicit GEMM, 256x128 tile, BK=32, 4 waves (2Mx2N), wave
// tile 128x64.  FORCED within-wave pipeline (r5's source-level attempt was
// undone by the scheduler: VGPR fell to 128 = next-tile reads sunk to use
// point, pipes serial at 1208cy/tile = 620 MFMA + 576 LDS).  Enforcement
// per guide rule #18 / HK pattern:
//   - next tile's 12 fragments via volatile inline-asm ds_read_b128
//     (per-fragment base VGPR; region folded into offset: immediate)
//   - counted s_waitcnt lgkmcnt(12): DS retires in-order, so <=12
//     outstanding => previous tile's reads (this tile's operands) complete;
//     the 12 new reads drain under the 620cy MFMA cluster
//   - sched_barrier(0) after the waitcnt (else hipcc hoists MFMA above it)
//   - STAGE after the waitcnt: DMA to region t%3 issues only after this
//     wave's reads from that region are confirmed complete
// Ring-3 LDS 72 KiB, 2 blocks/CU co-resident, grid 768 = 3 blocks/CU.
// ONE barrier per K-tile, counted vmcnt(6).  T2 swizzle slot ^= (row>>1)&3
// (verified 0-conflict), bijective XCD swizzle.  K: tap-major, 288x32.
// conv 0/1 (Q/K): out[b][o][s]; conv 2 (V): out[b][s][o].
// ---------------------------------------------------------------------------
__global__ __launch_bounds__(256, 2) void conv_gemm_td(
    const short* __restrict__ WpQ, const short* __restrict__ WpK, const short* __restrict__ WpV,
    const short* __restrict__ xPq, const short* __restrict__ xPk, const short* __restrict__ xPv,
    short* __restrict__ cQ, short* __restrict__ cK, short* __restrict__ cVT,
    const float* __restrict__ bq, const float* __restrict__ bk, const float* __restrict__ bv,
    int convSel) {
  __shared__ short lds[36864];  // 72 KiB: 3 regions x (A[256][32] + B[128][32])
  int tid = threadIdx.x, lane = tid & 63, wid = tid >> 6;

  // ---- T1: bijective XCD swizzle on flattened grid id ----
  int fid = blockIdx.x + (blockIdx.y << 2) + ((int)blockIdx.z << 5);
  int nwg = (int)gridDim.z << 5;          // 768 fused / 256 per-conv; %8==0
  int cpx = nwg >> 3;
  int swz = (fid & 7) * cpx + (fid >> 3);
  int mtile = swz & 3, ntile = (swz >> 2) & 7, z = swz >> 5;

  int conv = convSel >= 0 ? convSel : (z >> 3);
  int b = convSel >= 0 ? z : (z & 7);
  const short* Wp = conv == 0 ? WpQ : (conv == 1 ? WpK : WpV);
  const short* xP = conv == 0 ? xPq : (conv == 1 ? xPk : xPv);
  short* out = conv == 0 ? cQ : (conv == 1 ? cK : cVT);
  const float* bias = conv == 0 ? bq : (conv == 1 ? bk : bv);
  int XisA = (conv == 2);
  int mbase = mtile * 256, nbase = ntile * 128;
  const short* xb = xP + (size_t)b * 1183744;

  // ---- staging precompute (source pre-swizzled; DMA dest linear) ----
  int srow = tid >> 2;
  int lsl = (tid & 3) ^ ((tid >> 3) & 3);
  int gcol = lsl * 8;
  const short* pA0; const short* pB0;
  ptrdiff_t jA, jB;
  if (!XisA) {  // A = weights (o), B = tokens
    pA0 = Wp + (size_t)(mbase + srow) * 1024 + gcol;
    jA = 65536;   // 64 weight rows
    int tok = nbase + srow;
    pB0 = xb + (size_t)(((tok >> 5) + 1) * 34 + (tok & 31) + 1) * 1024 + gcol;
    jB = 69632;   // 64 tokens = +68 padded rows
  } else {      // A = tokens, B = weights (o)
    int ta = mbase + srow;
    pA0 = xb + (size_t)(((ta >> 5) + 1) * 34 + (ta & 31) + 1) * 1024 + gcol;
    jA = 69632;
    pB0 = Wp + (size_t)(nbase + srow) * 1024 + gcol;
    jB = 65536;
  }
  int sdst = tid * 8;  // DMA dest (shorts): wave-uniform base + lane*16B

  // ---- compute-read offsets, swizzle folded per-lane ----
  int pslot = (((lane >> 4) ^ ((lane >> 1) & 3)) << 3);
  int wr = wid >> 1, wc = wid & 1;                        // 2M x 2N waves
  int rdA = (wr * 128 + (lane & 15)) * 32 + pslot;        // shorts
  int rdB = 8192 + (wc * 64 + (lane & 15)) * 32 + pslot;  // shorts
  // low 32 bits of generic LDS pointer = segment offset (HK idiom)
  unsigned vA = (unsigned)(size_t)&lds[rdA];
  unsigned vB = (unsigned)(size_t)&lds[rdB];

  f32x4 acc[8][4] = {};
  bh8 aX[8], bX[4], aY[8], bY[4];

#define STAGE(U, SRB) do { \
    int u_ = (U); \
    int tap_ = u_ >> 5, kk_ = (u_ & 31) << 5; \
    int ty_ = (tap_ * 11) >> 5; \
    ptrdiff_t dW_ = (ptrdiff_t)tap_ * 1048576 + kk_; \
    ptrdiff_t dX_ = (ptrdiff_t)(ty_ * 34 + (tap_ - ty_ * 3) - 35) * 1024 + kk_; \
    ptrdiff_t dA_ = XisA ? dX_ : dW_, dB_ = XisA ? dW_ : dX_; \
    short* du_ = &lds[(SRB) + sdst]; \
    g2l16(pA0 + dA_,          du_); \
    g2l16(pA0 + dA_ + jA,     du_ + 2048); \
    g2l16(pA0 + dA_ + 2 * jA, du_ + 4096); \
    g2l16(pA0 + dA_ + 3 * jA, du_ + 6144); \
    g2l16(pB0 + dB_,          du_ + 8192); \
    g2l16(pB0 + dB_ + jB,     du_ + 10240); \
  } while (0)

// RO = region byte offset (0 / 24576 / 49152); A frag imm: (mt&3)*1024 +
// (mt>>2)*4096; B frag imm: nt*1024.  Max imm 49152+7168 < 65536.
#define LOADF(AF, BF, RO) do { \
    dsr(AF[0], vA, (RO) + 0);    dsr(AF[1], vA, (RO) + 1024); \
    dsr(AF[2], vA, (RO) + 2048); dsr(AF[3], vA, (RO) + 3072); \
    dsr(AF[4], vA, (RO) + 4096); dsr(AF[5], vA, (RO) + 5120); \
    dsr(AF[6], vA, (RO) + 6144); dsr(AF[7], vA, (RO) + 7168); \
    dsr(BF[0], vB, (RO) + 0);    dsr(BF[1], vB, (RO) + 1024); \
    dsr(BF[2], vB, (RO) + 2048); dsr(BF[3], vB, (RO) + 3072); \
  } while (0)

#define MFMA32(AF, BF) do { \
    __builtin_amdgcn_s_setprio(1); \
    _Pragma("unroll") for (int mt = 0; mt < 8; ++mt) { \
      _Pragma("unroll") for (int nt = 0; nt < 4; ++nt) \
        acc[mt][nt] = __builtin_amdgcn_mfma_f32_16x16x32_bf16( \
            AF[mt], BF[nt], acc[mt][nt], 0, 0, 0); \
    } \
    __builtin_amdgcn_s_setprio(0); \
  } while (0)

// TILE t: issue frags(t+1) reads; wait prev reads (counted); stage t+3; MFMA t.
#define TILEBODY(RO, T, AFc, BFc, AFn, BFn, DOSTAGE, SRB, WSTR) do { \
    LOADF(AFn, BFn, RO); \
    asm volatile("s_waitcnt lgkmcnt(12)" ::: "memory"); \
    __builtin_amdgcn_sched_barrier(0); \
    if (DOSTAGE) STAGE((T) + 3, SRB); \
    MFMA32(AFc, BFc); \
    asm volatile(WSTR ::: "memory"); \
    barrier_raw(); \
  } while (0)

  // ---- prologue: stage tiles 0,1,2; preload tile-0 frags into set X ----
  STAGE(0, 0);
  STAGE(1, 12288);
  STAGE(2, 24576);
  asm volatile("s_waitcnt vmcnt(6)" ::: "memory");  // tiles 0 AND 1 resident
  barrier_raw();
  LOADF(aX, bX, 0);

  // ---- main loop: 282 K-tiles, unroll 6 (ring-3 x ping-pong-2) ----
#pragma unroll 1
  for (int it = 0; it < 47; ++it) {
    int t0 = it * 6;
    TILEBODY(24576, t0 + 0, aX, bX, aY, bY, true, 0,     "s_waitcnt vmcnt(6)");
    TILEBODY(49152, t0 + 1, aY, bY, aX, bX, true, 12288, "s_waitcnt vmcnt(6)");
    TILEBODY(0,     t0 + 2, aX, bX, aY, bY, true, 24576, "s_waitcnt vmcnt(6)");
    TILEBODY(24576, t0 + 3, aY, bY, aX, bX, true, 0,     "s_waitcnt vmcnt(6)");
    TILEBODY(49152, t0 + 4, aX, bX, aY, bY, true, 12288, "s_waitcnt vmcnt(6)");
    TILEBODY(0,     t0 + 5, aY, bY, aX, bX, true, 24576, "s_waitcnt vmcnt(6)");
  }
  // ---- tail: tiles 282..287 (stage ends at 287; vmcnt drains) ----
  TILEBODY(24576, 282, aX, bX, aY, bY, true,  0,     "s_waitcnt vmcnt(6)");
  TILEBODY(49152, 283, aY, bY, aX, bX, true,  12288, "s_waitcnt vmcnt(6)");
  TILEBODY(0,     284, aX, bX, aY, bY, true,  24576, "s_waitcnt vmcnt(6)");
  TILEBODY(24576, 285, aY, bY, aX, bX, false, 0,     "s_waitcnt vmcnt(0)");
  TILEBODY(49152, 286, aX, bX, aY, bY, false, 0,     "");
  asm volatile("s_waitcnt lgkmcnt(0)" ::: "memory");  // tile 287 frags ready
  __builtin_amdgcn_sched_barrier(0);
  MFMA32(aY, bY);  // tile 287

#undef TILEBODY
#undef MFMA32
#undef LOADF
#undef STAGE

  // ---- epilogue ----
  size_t ob = (size_t)b * 1048576;
#pragma unroll
  for (int mt = 0; mt < 8; ++mt) {
#pragma unroll
    for (int nt = 0; nt < 4; ++nt) {
      int m0 = mbase + wr * 128 + mt * 16 + ((lane >> 4) << 2);
      int nn = nbase + wc * 64 + nt * 16 + (lane & 15);
#pragma unroll
      for (int r = 0; r < 4; ++r) {
        float bvv = bias[XisA ? nn : (m0 + r)];
        out[ob + (size_t)(m0 + r) * 1024 + nn] = f2bf(acc[mt][nt][r] + bvv);
      }
    }
  }
}

// ---------------------------------------------------------------------------
// Attention, SINGLE-PASS online softmax.  grid (16,16,8) = (qtile, head, b).
// ---------------------------------------------------------------------------
__global__ __launch_bounds__(256) void attn(
    const short* __restrict__ Qc, const short* __restrict__ Kc,
    const short* __restrict__ VT, const unsigned* __restrict__ Mp,
    short* __restrict__ AO) {
  __shared__ short sQ[64][72];
  __shared__ short sK[128][72];
  __shared__ short sV[64][136];
  __shared__ short sP[64][136];
  int tid = threadIdx.x, lane = tid & 63, w = tid >> 6;
  int qbase = blockIdx.x * 64, h = blockIdx.y, b = blockIdx.z;
  int j0 = h * 64;
  const short* Qb = Qc + (size_t)b * 1048576;
  const short* Kb = Kc + (size_t)b * 1048576;
  const short* Vb = VT + (size_t)b * 1048576;
  const unsigned* Mpb = Mp + (size_t)b * 32768;
  const float scale = 0.125f;  // 1/sqrt(64)

#pragma unroll
  for (int i = 0; i < 2; ++i) {
    int cid = tid + i * 256;
    int row = cid >> 3, co = (cid & 7) * 8;
    *(bh8*)&sQ[row][co] = *(const bh8*)(Qb + (size_t)(qbase + row) * 1024 + j0 + co);
  }
  __syncthreads();

  int tg = qbase + w * 16 + (lane & 15);  // stats row for this lane
  int rsel = ((lane >> 4) << 2);          // C-layout row base (quad*4)
  float mrow = -3.0e38f, lrow = 0.0f;
  f32x4 oacc[4] = {};

  for (int st = 0; st < 8; ++st) {
#pragma unroll
    for (int i = 0; i < 4; ++i) {
      int cid = tid + i * 256;
      int row = cid >> 3, co = (cid & 7) * 8;
      *(bh8*)&sK[row][co] = *(const bh8*)(Kb + (size_t)(st * 128 + row) * 1024 + j0 + co);
      int vrow = cid >> 4, vco = (cid & 15) * 8;
      *(bh8*)&sV[vrow][vco] = *(const bh8*)(Vb + (size_t)(j0 + vrow) * 1024 + st * 128 + vco);
    }
    __syncthreads();

    f32x4 sacc[8];
#pragma unroll
    for (int mt = 0; mt < 8; ++mt) {
      f32x4 a = {0.f, 0.f, 0.f, 0.f};
      bh8 kf = *(const bh8*)&sK[mt * 16 + (lane & 15)][(lane >> 4) * 8];
      bh8 qf = *(const bh8*)&sQ[w * 16 + (lane & 15)][(lane >> 4) * 8];
      a = __builtin_amdgcn_mfma_f32_16x16x32_bf16(kf, qf, a, 0, 0, 0);
      kf = *(const bh8*)&sK[mt * 16 + (lane & 15)][32 + (lane >> 4) * 8];
      qf = *(const bh8*)&sQ[w * 16 + (lane & 15)][32 + (lane >> 4) * 8];
      a = __builtin_amdgcn_mfma_f32_16x16x32_bf16(kf, qf, a, 0, 0, 0);
      sacc[mt] = a;
    }

    uint4 Mw = *(const uint4*)(Mpb + (size_t)tg * 32 + st * 4);
    float tmax = -3.0e38f;
#pragma unroll
    for (int mt = 0; mt < 8; ++mt) {
      unsigned mwv = ((const unsigned*)&Mw)[mt >> 1] >> ((mt & 1) * 16 + rsel);
      f32x4 vv;
      vv[0] = (mwv & 1u) ? sacc[mt][0] * scale : -1e9f;
      vv[1] = (mwv & 2u) ? sacc[mt][1] * scale : -1e9f;
      vv[2] = (mwv & 4u) ? sacc[mt][2] * scale : -1e9f;
      vv[3] = (mwv & 8u) ? sacc[mt][3] * scale : -1e9f;
      sacc[mt] = vv;
      tmax = fmaxf(tmax, fmaxf(fmaxf(vv[0], vv[1]), fmaxf(vv[2], vv[3])));
    }
    tmax = fmaxf(tmax, __shfl_xor(tmax, 16, 64));
    tmax = fmaxf(tmax, __shfl_xor(tmax, 32, 64));
    float mnew = fmaxf(mrow, tmax);
    float alpha = __expf(fminf(mrow - mnew, 0.f));

    float sum = 0.f;
    uint4 Mw2 = Mw;
#pragma unroll
    for (int mt = 0; mt < 8; ++mt) {
      unsigned mwv = ((const unsigned*)&Mw2)[mt >> 1] >> ((mt & 1) * 16 + rsel);
      float p0 = (mwv & 1u) ? __expf(fminf(sacc[mt][0] - mnew, 0.f)) : 0.f;
      float p1 = (mwv & 2u) ? __expf(fminf(sacc[mt][1] - mnew, 0.f)) : 0.f;
      float p2 = (mwv & 4u) ? __expf(fminf(sacc[mt][2] - mnew, 0.f)) : 0.f;
      float p3 = (mwv & 8u) ? __expf(fminf(sacc[mt][3] - mnew, 0.f)) : 0.f;
      sum += (p0 + p1) + (p2 + p3);
      bh4 p; p[0] = f2bf(p0); p[1] = f2bf(p1); p[2] = f2bf(p2); p[3] = f2bf(p3);
      *(bh4*)&sP[w * 16 + (lane & 15)][mt * 16 + rsel] = p;
    }
    sum += __shfl_xor(sum, 16, 64);
    sum += __shfl_xor(sum, 32, 64);
    lrow = lrow * alpha + sum;
    mrow = mnew;

    float al[4];
#pragma unroll
    for (int r = 0; r < 4; ++r) al[r] = __shfl(alpha, rsel + r, 64);
#pragma unroll
    for (int nt = 0; nt < 4; ++nt)
#pragma unroll
      for (int r = 0; r < 4; ++r) oacc[nt][r] *= al[r];
    __syncthreads();

#pragma unroll
    for (int k0 = 0; k0 < 4; ++k0) {
      bh8 pf = *(const bh8*)&sP[w * 16 + (lane & 15)][k0 * 32 + (lane >> 4) * 8];
#pragma unroll
      for (int nt = 0; nt < 4; ++nt) {
        bh8 vf = *(const bh8*)&sV[nt * 16 + (lane & 15)][k0 * 32 + (lane >> 4) * 8];
        oacc[nt] = __builtin_amdgcn_mfma_f32_16x16x32_bf16(pf, vf, oacc[nt], 0, 0, 0);
      }
    }
    __syncthreads();
  }

  float rl[4];
#pragma unroll
  for (int r = 0; r < 4; ++r) rl[r] = 1.0f / __shfl(lrow, rsel + r, 64);
  size_t ob = (size_t)b * 1048576;
#pragma unroll
  for (int nt = 0; nt < 4; ++nt) {
    int j = nt * 16 + (lane & 15);
    int t0 = qbase + w * 16 + rsel;
#pragma unroll
    for (int r = 0; r < 4; ++r)
      AO[ob + (size_t)(t0 + r) * 1024 + j0 + j] = f2bf(oacc[nt][r] * rl[r]);
  }
}

// ---------------------------------------------------------------------------
// Final projection: out[r][o] = sum_m A[r][m] * Wo[o][m] + bo[o]   (f32 out)
// ---------------------------------------------------------------------------
__global__ __launch_bounds__(256) void gemm_bt(
    const short* __restrict__ A, const short* __restrict__ Bm,
    float* __restrict__ out, const float* __restrict__ bias) {
  __shared__ short sA[4096];
  __shared__ short sB[4096];
  int tid = threadIdx.x, lane = tid & 63, w = tid >> 6;
  int mbase = blockIdx.x * 128, nbase = blockIdx.y * 128;
  int colsh = (lane & 3) * 8;
  int ldsoff[2]; const short* ap[2]; const short* bp[2];
#pragma unroll
  for (int i = 0; i < 2; ++i) {
    int row = 32 * w + 16 * i + (lane >> 2);
    ldsoff[i] = (2 * w + i) * 512 + lane * 8;
    ap[i] = A + (size_t)(mbase + row) * 1024 + colsh;
    bp[i] = Bm + (size_t)(nbase + row) * 1024 + colsh;
  }
  f32x4 acc[4][4] = {};
  int wm = (w >> 1) * 64, wn = (w & 1) * 64;
  for (int kt = 0; kt < 1024; kt += 32) {
#pragma unroll
    for (int i = 0; i < 2; ++i) {
      g2l16(ap[i] + kt, sA + ldsoff[i]);
      g2l16(bp[i] + kt, sB + ldsoff[i]);
    }
    __syncthreads();
    bh8 af[4], bfr[4];
#pragma unroll
    for (int mt = 0; mt < 4; ++mt)
      af[mt] = *(const bh8*)&sA[(wm + mt * 16 + (lane & 15)) * 32 + (lane >> 4) * 8];
#pragma unroll
    for (int nt = 0; nt < 4; ++nt)
      bfr[nt] = *(const bh8*)&sB[(wn + nt * 16 + (lane & 15)) * 32 + (lane >> 4) * 8];
#pragma unroll
    for (int mt = 0; mt < 4; ++mt)
#pragma unroll
      for (int nt = 0; nt < 4; ++nt)
        acc[mt][nt] = __builtin_amdgcn_mfma_f32_16x16x32_bf16(af[mt], bfr[nt], acc[mt][nt], 0, 0, 0);
    __syncthreads();
  }
#pragma unroll
  for (int mt = 0; mt < 4; ++mt) {
#pragma unroll
    for (int nt = 0; nt < 4; ++nt) {
      int m0 = mbase + wm + mt * 16 + ((lane >> 4) << 2);
      int n = nbase + wn + nt * 16 + (lane & 15);
      float bv = bias[n];
#pragma unroll
      for (int r = 0; r < 4; ++r)
        out[(size_t)(m0 + r) * 1024 + n] = acc[mt][nt][r] + bv;
    }
  }
}

// ---------------------------------------------------------------------------
extern "C" void kernel_launch(void* const* d_in, const int* in_sizes, int n_in,
                              void* d_out, int out_size, void* d_ws, size_t ws_size,
                              hipStream_t stream) {
  (void)in_sizes; (void)n_in; (void)out_size;
  const float* q    = (const float*)d_in[0];
  const float* k    = (const float*)d_in[1];
  const float* v    = (const float*)d_in[2];
  const float* Wq   = (const float*)d_in[3];
  const float* bq   = (const float*)d_in[4];
  const float* Wk   = (const float*)d_in[5];
  const float* bk   = (const float*)d_in[6];
  const float* Wv   = (const float*)d_in[7];
  const float* bv   = (const float*)d_in[8];
  const float* Wo   = (const float*)d_in[9];
  const float* bo   = (const float*)d_in[10];
  const int*   mask = (const int*)d_in[11];
  float* out = (float*)d_out;
  char* ws = (char*)d_ws;

  const size_t XPE = 1156ull * 1024 * 8;      // padded tensor elems (9,469,952)
  const size_t XPB = XPE * 2;                 // 18,939,904 B
  const size_t WPE = 9ull * 1048576;          // Wp elems
  short* xPq = (short*)ws;
  short* xPk = xPq + XPE;
  short* xPv = xPk + XPE;
  short* WpQ = (short*)(ws + 3 * XPB);
  short* WpK = WpQ + WPE;
  short* WpV = WpK + WPE;
  char* p2 = ws + 3 * XPB + 3 * WPE * 2;      // 113,442,816

  bool fused = ws_size >= 167000000ull;
  short *cQ, *cK, *cVT, *WoB, *AO; unsigned* Mpk;
  if (fused) {
    cQ  = (short*)(p2);
    cK  = (short*)(p2 + 16777216);
    cVT = (short*)(p2 + 33554432);
    WoB = (short*)(p2 + 50331648);
    Mpk = (unsigned*)(p2 + 52428800);
    AO  = xPq;                                 // dead after conv
  } else {
    cQ  = (short*)(p2);
    WoB = (short*)(p2 + 16777216);
    Mpk = (unsigned*)(p2 + 18874368);
    cK  = xPq;   // sequential: xPq dead after conv Q
    cVT = xPk;   // xPk dead after conv K
    AO  = xPv;   // xPv dead after conv V
  }

  zero_halo<<<dim3(66, 24), dim3(256), 0, stream>>>(xPq);
  transpose3<<<dim3(16, 16, 24), dim3(256), 0, stream>>>(q, k, v, xPq, xPk, xPv);
  wperm3<<<dim3(4096, 3), dim3(256), 0, stream>>>(Wq, Wk, Wv, WpQ, WpK, WpV);
  cvt_bf<<<dim3(1024), dim3(256), 0, stream>>>(Wo, WoB);
  mask_pack<<<dim3(1024), dim3(256), 0, stream>>>(mask, Mpk);
  if (fused) {
    conv_gemm_td<<<dim3(4, 8, 24), dim3(256), 0, stream>>>(
        WpQ, WpK, WpV, xPq, xPk, xPv, cQ, cK, cVT, bq, bk, bv, -1);
  } else {
    conv_gemm_td<<<dim3(4, 8, 8), dim3(256), 0, stream>>>(
        WpQ, WpK, WpV, xPq, xPk, xPv, cQ, cK, cVT, bq, bk, bv, 0);
    conv_gemm_td<<<dim3(4, 8, 8), dim3(256), 0, stream>>>(
        WpQ, WpK, WpV, xPq, xPk, xPv, cQ, cK, cVT, bq, bk, bv, 1);
    conv_gemm_td<<<dim3(4, 8, 8), dim3(256), 0, stream>>>(
        WpQ, WpK, WpV, xPq, xPk, xPv, cQ, cK, cVT, bq, bk, bv, 2);
  }
  attn<<<dim3(16, 16, 8), dim3(256), 0, stream>>>(cQ, cK, cVT, Mpk, AO);
  gemm_bt<<<dim3(64, 8), dim3(256), 0, stream>>>(AO, WoB, out, bo);
}

// Round 8
// 785.057 us; speedup vs baseline: 1.0507x; 1.0507x over previous
//
#include <hip/hip_runtime.h>

typedef __attribute__((ext_vector_type(8))) short bh8;
typedef __attribute__((ext_vector_type(4))) short bh4;
typedef __attribute__((ext_vector_type(4))) float f32x4;

__device__ __forceinline__ short f2bf(float f) {
  union { float f; unsigned u; } a; a.f = f;
  unsigned r = a.u + 0x7FFFu + ((a.u >> 16) & 1u);
  return (short)(r >> 16);
}

// async global->LDS DMA, 16B per lane; LDS dest must be wave-uniform base + lane*16
__device__ __forceinline__ void g2l16(const short* g, short* l) {
  __builtin_amdgcn_global_load_lds(
      (const __attribute__((address_space(1))) void*)g,
      (__attribute__((address_space(3))) void*)l, 16, 0, 0);
}

// raw barrier: no vmcnt/lgkmcnt drain (unlike __syncthreads), compiler-fenced
__device__ __forceinline__ void barrier_raw() {
  asm volatile("" ::: "memory");
  __builtin_amdgcn_s_barrier();
  asm volatile("" ::: "memory");
}

// ---------------------------------------------------------------------------
// Zero only the 132 halo rows of each padded tensor (q,k,v are contiguous).
// ---------------------------------------------------------------------------
__global__ __launch_bounds__(256) void zero_halo(short* __restrict__ xP) {
  int z = blockIdx.y;  // (tensor*8 + b), buffers contiguous
  short* base = xP + (size_t)z * 1183744;
  int ri = blockIdx.x * 2 + (threadIdx.x >> 7);  // 0..131
  int row;
  if (ri < 34) row = ri;                           // y = 0
  else if (ri < 68) row = 1122 + (ri - 34);        // y = 33
  else { int j = ri - 68; int y = (j >> 1) + 1; int x = (j & 1) ? 33 : 0; row = y * 34 + x; }
  int col = (threadIdx.x & 127) * 8;
  bh8 zv = {0, 0, 0, 0, 0, 0, 0, 0};
  *(bh8*)(base + (size_t)row * 1024 + col) = zv;
}

// ---------------------------------------------------------------------------
// Prep 1: x[b][c][32*32] (f32) -> xP[b][(y+1)*34+(x+1)][c] (bf16), halo=0.
// ---------------------------------------------------------------------------
__global__ __launch_bounds__(256) void transpose3(
    const float* __restrict__ q, const float* __restrict__ k, const float* __restrict__ v,
    short* __restrict__ qP, short* __restrict__ kP, short* __restrict__ vP) {
  int z = blockIdx.z; int tensor = z >> 3, b = z & 7;
  const float* src = tensor == 0 ? q : (tensor == 1 ? k : v);
  short* dst = tensor == 0 ? qP : (tensor == 1 ? kP : vP);
  src += (size_t)b * 1048576; dst += (size_t)b * 1183744;  // 1156*1024
  int row0 = blockIdx.y * 64;  // c
  int col0 = blockIdx.x * 64;  // s
  __shared__ short t[64][72];
  int tid = threadIdx.x;
#pragma unroll
  for (int i = 0; i < 2; ++i) {
    int cid = tid + i * 256;
    int r = cid >> 3, co = (cid & 7) * 8;
    const float* p = src + (size_t)(row0 + r) * 1024 + col0 + co;
    float4 f0 = *(const float4*)(p);
    float4 f1 = *(const float4*)(p + 4);
    t[co + 0][r] = f2bf(f0.x); t[co + 1][r] = f2bf(f0.y);
    t[co + 2][r] = f2bf(f0.z); t[co + 3][r] = f2bf(f0.w);
    t[co + 4][r] = f2bf(f1.x); t[co + 5][r] = f2bf(f1.y);
    t[co + 6][r] = f2bf(f1.z); t[co + 7][r] = f2bf(f1.w);
  }
  __syncthreads();
#pragma unroll
  for (int i = 0; i < 2; ++i) {
    int cid = tid + i * 256;
    int sr = cid >> 3, cc = (cid & 7) * 8;
    bh8 val = *(const bh8*)&t[sr][cc];
    int tok = col0 + sr;
    int pr = ((tok >> 5) + 1) * 34 + (tok & 31) + 1;
    *(bh8*)(dst + (size_t)pr * 1024 + row0 + cc) = val;
  }
}

// ---------------------------------------------------------------------------
// Prep 2: Wp[tap][o][c] (bf16) = W[o][c][tap] (f32).  grid (4096, 3)
// ---------------------------------------------------------------------------
__global__ __launch_bounds__(256) void wperm3(
    const float* __restrict__ Wq, const float* __restrict__ Wk, const float* __restrict__ Wv,
    short* __restrict__ WpQ, short* __restrict__ WpK, short* __restrict__ WpV) {
  int z = blockIdx.y;
  const float* W = z == 0 ? Wq : (z == 1 ? Wk : Wv);
  short* Wp = z == 0 ? WpQ : (z == 1 ? WpK : WpV);
  int idx = blockIdx.x * 256 + threadIdx.x;  // (o,c) flat, 0..1M
  const float* wsrc = W + (size_t)idx * 9;
#pragma unroll
  for (int t = 0; t < 9; ++t) Wp[(size_t)t * 1048576 + idx] = f2bf(wsrc[t]);
}

// ---------------------------------------------------------------------------
// Prep 3: Wo f32 -> bf16 flat.  grid (1024)
// ---------------------------------------------------------------------------
__global__ __launch_bounds__(256) void cvt_bf(const float* __restrict__ src,
                                              short* __restrict__ dst) {
  int idx = (blockIdx.x * 256 + threadIdx.x) * 4;
  float4 f = *(const float4*)(src + idx);
  bh4 o; o[0] = f2bf(f.x); o[1] = f2bf(f.y); o[2] = f2bf(f.z); o[3] = f2bf(f.w);
  *(bh4*)(dst + idx) = o;
}

// ---------------------------------------------------------------------------
// Prep 4: pack mask int32 -> bits. word idx = (b*1024 + t)*32 + (s>>5)
// ---------------------------------------------------------------------------
__global__ __launch_bounds__(256) void mask_pack(const int* __restrict__ m,
                                                 unsigned* __restrict__ mp) {
  int idx = blockIdx.x * 256 + threadIdx.x;
  const int* src = m + (size_t)idx * 32;
  unsigned wv = 0;
#pragma unroll
  for (int j = 0; j < 32; j += 4) {
    int4 a = *(const int4*)(src + j);
    wv |= ((unsigned)(a.x & 1) << j) | ((unsigned)(a.y & 1) << (j + 1)) |
          ((unsigned)(a.z & 1) << (j + 2)) | ((unsigned)(a.w & 1) << (j + 3));
  }
  mp[idx] = wv;
}

// ---------------------------------------------------------------------------
// Fused conv3x3 implicit GEMM — REVERTED to the round-3 best (432us, VGPR 64,
// MfmaUtil 51%, 0 conflicts).  256x128 tile, BK=32, 8 waves (4Mx2N), ring-3
// LDS 72 KiB, 2 blocks/CU co-resident, grid 768 = 3 blocks/CU.  ONE barrier
// per K-tile, counted vmcnt(3).  T2 swizzle slot ^= (row>>1)&3, bijective
// XCD swizzle.  K: tap-major, 288x32.  (r4-r7 restructurings — 4-wave 128x64,
// source pipelining, forced asm pipelining — all measured 435-455us: worse.)
// conv 0/1 (Q/K): out[b][o][s]; conv 2 (V): out[b][s][o].
// ---------------------------------------------------------------------------
__global__ __launch_bounds__(512, 4) void conv_gemm_td(
    const short* __restrict__ WpQ, const short* __restrict__ WpK, const short* __restrict__ WpV,
    const short* __restrict__ xPq, const short* __restrict__ xPk, const short* __restrict__ xPv,
    short* __restrict__ cQ, short* __restrict__ cK, short* __restrict__ cVT,
    const float* __restrict__ bq, const float* __restrict__ bk, const float* __restrict__ bv,
    int convSel) {
  __shared__ short lds[36864];  // 72 KiB: 3 regions x (A[256][32] + B[128][32])
  int tid = threadIdx.x, lane = tid & 63, wid = tid >> 6;

  // ---- T1: bijective XCD swizzle on flattened grid id ----
  int fid = blockIdx.x + (blockIdx.y << 2) + ((int)blockIdx.z << 5);
  int nwg = (int)gridDim.z << 5;          // 768 fused / 256 per-conv; %8==0
  int cpx = nwg >> 3;
  int swz = (fid & 7) * cpx + (fid >> 3);
  int mtile = swz & 3, ntile = (swz >> 2) & 7, z = swz >> 5;

  int conv = convSel >= 0 ? convSel : (z >> 3);
  int b = convSel >= 0 ? z : (z & 7);
  const short* Wp = conv == 0 ? WpQ : (conv == 1 ? WpK : WpV);
  const short* xP = conv == 0 ? xPq : (conv == 1 ? xPk : xPv);
  short* out = conv == 0 ? cQ : (conv == 1 ? cK : cVT);
  const float* bias = conv == 0 ? bq : (conv == 1 ? bk : bv);
  int XisA = (conv == 2);
  int mbase = mtile * 256, nbase = ntile * 128;
  const short* xb = xP + (size_t)b * 1183744;

  // ---- staging precompute (source pre-swizzled; DMA dest linear) ----
  int srow = tid >> 2;
  int lsl = (tid & 3) ^ ((tid >> 3) & 3);
  int gcol = lsl * 8;
  const short* pA0; const short* pA1; const short* pB0;
  if (!XisA) {  // A = weights (o), B = tokens
    pA0 = Wp + (size_t)(mbase + srow) * 1024 + gcol;
    pA1 = Wp + (size_t)(mbase + 128 + srow) * 1024 + gcol;
    int tok = nbase + srow;
    pB0 = xb + (size_t)(((tok >> 5) + 1) * 34 + (tok & 31) + 1) * 1024 + gcol;
  } else {      // A = tokens, B = weights (o)
    int ta = mbase + srow, tb = mbase + 128 + srow;
    pA0 = xb + (size_t)(((ta >> 5) + 1) * 34 + (ta & 31) + 1) * 1024 + gcol;
    pA1 = xb + (size_t)(((tb >> 5) + 1) * 34 + (tb & 31) + 1) * 1024 + gcol;
    pB0 = Wp + (size_t)(nbase + srow) * 1024 + gcol;
  }
  int sdst = tid * 8;  // DMA dest (shorts): uniform base + lane*16B

  // ---- compute-read offsets (shorts), swizzle folded per-lane ----
  int pslot = (((lane >> 4) ^ ((lane >> 1) & 3)) << 3);
  int wr = wid >> 1, wc = wid & 1;                        // 4M x 2N waves
  int rdA = (wr * 64 + (lane & 15)) * 32 + pslot;         // + mt*512
  int rdB = 8192 + (wc * 64 + (lane & 15)) * 32 + pslot;  // + nt*512

  f32x4 acc[4][4] = {};

#define STAGE(U, SRB) do { \
    int u_ = (U); \
    int tap_ = u_ >> 5, kk_ = (u_ & 31) << 5; \
    int ty_ = (tap_ * 11) >> 5; \
    ptrdiff_t dW_ = (ptrdiff_t)tap_ * 1048576 + kk_; \
    ptrdiff_t dX_ = (ptrdiff_t)(ty_ * 34 + (tap_ - ty_ * 3) - 35) * 1024 + kk_; \
    ptrdiff_t dA_ = XisA ? dX_ : dW_, dB_ = XisA ? dW_ : dX_; \
    short* du_ = &lds[(SRB) + sdst]; \
    g2l16(pA0 + dA_, du_); \
    g2l16(pA1 + dA_, du_ + 4096); \
    g2l16(pB0 + dB_, du_ + 8192); \
  } while (0)

  // ---- prologue: stage tiles 0,1 into regions 0,1 ----
  STAGE(0, 0);
  STAGE(1, 12288);
  asm volatile("s_waitcnt vmcnt(3)" ::: "memory");  // tile 0 resident
  barrier_raw();

#define TILEBODY(RB, T, DOSTAGE, SRB, WSTR) do { \
    const short* Lp = &lds[(RB)]; \
    bh8 afr[4], bfr[4]; \
    _Pragma("unroll") for (int mt = 0; mt < 4; ++mt) \
      afr[mt] = *(const bh8*)(Lp + rdA + mt * 512); \
    _Pragma("unroll") for (int nt = 0; nt < 4; ++nt) \
      bfr[nt] = *(const bh8*)(Lp + rdB + nt * 512); \
    if (DOSTAGE) STAGE((T) + 2, SRB); \
    __builtin_amdgcn_s_setprio(1); \
    _Pragma("unroll") for (int mt = 0; mt < 4; ++mt) { \
      _Pragma("unroll") for (int nt = 0; nt < 4; ++nt) \
        acc[mt][nt] = __builtin_amdgcn_mfma_f32_16x16x32_bf16( \
            afr[mt], bfr[nt], acc[mt][nt], 0, 0, 0); \
    } \
    __builtin_amdgcn_s_setprio(0); \
    asm volatile(WSTR ::: "memory"); \
    barrier_raw(); \
  } while (0)

  // ---- main loop: 288 K-tiles, ring-3, 1 barrier per tile ----
#pragma unroll 1
  for (int it = 0; it < 95; ++it) {
    int t0 = it * 3;
    TILEBODY(0,     t0 + 0, true, 24576, "s_waitcnt vmcnt(3)");
    TILEBODY(12288, t0 + 1, true, 0,     "s_waitcnt vmcnt(3)");
    TILEBODY(24576, t0 + 2, true, 12288, "s_waitcnt vmcnt(3)");
  }
  // tail: tiles 285..287 (drain 3 -> 0)
  TILEBODY(0,     285, true,  24576, "s_waitcnt vmcnt(3)");
  TILEBODY(12288, 286, false, 0,     "s_waitcnt vmcnt(0)");
  TILEBODY(24576, 287, false, 0,     "");

#undef TILEBODY
#undef STAGE

  // ---- epilogue ----
  size_t ob = (size_t)b * 1048576;
#pragma unroll
  for (int mt = 0; mt < 4; ++mt) {
#pragma unroll
    for (int nt = 0; nt < 4; ++nt) {
      int m0 = mbase + wr * 64 + mt * 16 + ((lane >> 4) << 2);
      int nn = nbase + wc * 64 + nt * 16 + (lane & 15);
#pragma unroll
      for (int r = 0; r < 4; ++r) {
        float bvv = bias[XisA ? nn : (m0 + r)];
        out[ob + (size_t)(m0 + r) * 1024 + nn] = f2bf(acc[mt][nt][r] + bvv);
      }
    }
  }
}

// ---------------------------------------------------------------------------
// Attention, SINGLE-PASS online softmax.  grid (16,16,8) = (qtile, head, b).
// NEW: DMA-staged K/V (global_load_lds), K ring-2 prefetched one tile ahead,
// V single-buffer staged at tile entry (consumed post-softmax).  Counted
// vmcnt(4) + barrier before PV (V resident, cross-wave); end-of-tile
// vmcnt(0)+barrier (K(t+1) drain — free, issued a full tile earlier).
// 2 barriers/tile (was 3) and zero register-round-trip staging.
// LDS K/V tiles are linear (DMA constraint) with the conv-verified 64B-row
// swizzle pslot = slot ^ ((row>>1)&3) on stage-source AND read (rule #21):
//   K region: [half][128][4 slots], V: [qtr k0][64][4 slots].
// Softmax / PV math identical to the verified kernel.
// ---------------------------------------------------------------------------
__global__ __launch_bounds__(256) void attn(
    const short* __restrict__ Qc, const short* __restrict__ Kc,
    const short* __restrict__ VT, const unsigned* __restrict__ Mp,
    short* __restrict__ AO) {
  __shared__ short sQ[64][72];
  __shared__ short sK[2][8192];   // ring-2: [half][128][32] each
  __shared__ short sV[8192];      // [4 qtr][64][32]
  __shared__ short sP[64][136];
  int tid = threadIdx.x, lane = tid & 63, w = tid >> 6;
  int qbase = blockIdx.x * 64, h = blockIdx.y, b = blockIdx.z;
  int j0 = h * 64;
  const short* Qb = Qc + (size_t)b * 1048576;
  const short* Kb = Kc + (size_t)b * 1048576;
  const short* Vb = VT + (size_t)b * 1048576;
  const unsigned* Mpb = Mp + (size_t)b * 32768;
  const float scale = 0.125f;  // 1/sqrt(64)

  // ---- sQ (vector loads, once) ----
#pragma unroll
  for (int i = 0; i < 2; ++i) {
    int cid = tid + i * 256;
    int row = cid >> 3, co = (cid & 7) * 8;
    *(bh8*)&sQ[row][co] = *(const bh8*)(Qb + (size_t)(qbase + row) * 1024 + j0 + co);
  }

  // ---- staging chunk pointers (4 chunks/thread for K and V) ----
  // chunk cid: K: half=cid>>9, row=(cid>>2)&127, pslot=cid&3,
  //            logical slot = pslot ^ ((row>>1)&3) = (cid&3)^((cid>>3)&3)
  //            V: qtr=cid>>8, row=(cid>>2)&63, same slot law.
  const short* kSrc[4]; const short* vSrc[4]; int cDst[4];
#pragma unroll
  for (int i = 0; i < 4; ++i) {
    int cid = tid + i * 256;
    int lsl = (cid & 3) ^ ((cid >> 3) & 3);
    int krow = (cid >> 2) & 127, khalf = cid >> 9;
    kSrc[i] = Kb + (size_t)krow * 1024 + j0 + khalf * 32 + lsl * 8;
    int vrow = (cid >> 2) & 63, vqtr = cid >> 8;
    vSrc[i] = Vb + (size_t)(j0 + vrow) * 1024 + vqtr * 32 + lsl * 8;
    cDst[i] = cid * 8;
  }

  // ---- stage K(0) into ring 0; full drain covers sQ stores too ----
#pragma unroll
  for (int i = 0; i < 4; ++i) g2l16(kSrc[i], &sK[0][cDst[i]]);
  __syncthreads();

  int tg = qbase + w * 16 + (lane & 15);  // stats row for this lane
  int rsel = ((lane >> 4) << 2);          // C-layout row base (quad*4)
  int ksel = (((lane >> 4) ^ ((lane >> 1) & 3)) << 3);  // swizzled slot (shorts)
  float mrow = -3.0e38f, lrow = 0.0f;
  f32x4 oacc[4] = {};

  for (int st = 0; st < 8; ++st) {
    // ---- issue K(st+1) prefetch and V(st) stage (8 DMA/thread) ----
    if (st < 7) {
      const short* ks = kSrc[0] + (size_t)(st + 1) * 131072;
      short* kd = &sK[(st + 1) & 1][0];
#pragma unroll
      for (int i = 0; i < 4; ++i)
        g2l16(kSrc[i] + (size_t)(st + 1) * 131072, kd + cDst[i]);
      (void)ks;
    }
#pragma unroll
    for (int i = 0; i < 4; ++i) g2l16(vSrc[i] + (size_t)st * 128, &sV[cDst[i]]);

    // ---- S^T tile from sK[st&1] ----
    const short* Kr = &sK[st & 1][0];
    f32x4 sacc[8];
#pragma unroll
    for (int mt = 0; mt < 8; ++mt) {
      f32x4 a = {0.f, 0.f, 0.f, 0.f};
      bh8 kf = *(const bh8*)(Kr + (mt * 16 + (lane & 15)) * 32 + ksel);
      bh8 qf = *(const bh8*)&sQ[w * 16 + (lane & 15)][(lane >> 4) * 8];
      a = __builtin_amdgcn_mfma_f32_16x16x32_bf16(kf, qf, a, 0, 0, 0);
      kf = *(const bh8*)(Kr + 4096 + (mt * 16 + (lane & 15)) * 32 + ksel);
      qf = *(const bh8*)&sQ[w * 16 + (lane & 15)][32 + (lane >> 4) * 8];
      a = __builtin_amdgcn_mfma_f32_16x16x32_bf16(kf, qf, a, 0, 0, 0);
      sacc[mt] = a;
    }

    // ---- mask + scale, tile max ----
    uint4 Mw = *(const uint4*)(Mpb + (size_t)tg * 32 + st * 4);
    float tmax = -3.0e38f;
#pragma unroll
    for (int mt = 0; mt < 8; ++mt) {
      unsigned mwv = ((const unsigned*)&Mw)[mt >> 1] >> ((mt & 1) * 16 + rsel);
      f32x4 vv;
      vv[0] = (mwv & 1u) ? sacc[mt][0] * scale : -1e9f;
      vv[1] = (mwv & 2u) ? sacc[mt][1] * scale : -1e9f;
      vv[2] = (mwv & 4u) ? sacc[mt][2] * scale : -1e9f;
      vv[3] = (mwv & 8u) ? sacc[mt][3] * scale : -1e9f;
      sacc[mt] = vv;
      tmax = fmaxf(tmax, fmaxf(fmaxf(vv[0], vv[1]), fmaxf(vv[2], vv[3])));
    }
    tmax = fmaxf(tmax, __shfl_xor(tmax, 16, 64));
    tmax = fmaxf(tmax, __shfl_xor(tmax, 32, 64));
    float mnew = fmaxf(mrow, tmax);
    float alpha = __expf(fminf(mrow - mnew, 0.f));

    // ---- unnormalized P' to LDS, per-lane partial row-sums ----
    float sum = 0.f;
#pragma unroll
    for (int mt = 0; mt < 8; ++mt) {
      unsigned mwv = ((const unsigned*)&Mw)[mt >> 1] >> ((mt & 1) * 16 + rsel);
      float p0 = (mwv & 1u) ? __expf(fminf(sacc[mt][0] - mnew, 0.f)) : 0.f;
      float p1 = (mwv & 2u) ? __expf(fminf(sacc[mt][1] - mnew, 0.f)) : 0.f;
      float p2 = (mwv & 4u) ? __expf(fminf(sacc[mt][2] - mnew, 0.f)) : 0.f;
      float p3 = (mwv & 8u) ? __expf(fminf(sacc[mt][3] - mnew, 0.f)) : 0.f;
      sum += (p0 + p1) + (p2 + p3);
      bh4 p; p[0] = f2bf(p0); p[1] = f2bf(p1); p[2] = f2bf(p2); p[3] = f2bf(p3);
      *(bh4*)&sP[w * 16 + (lane & 15)][mt * 16 + rsel] = p;
    }
    sum += __shfl_xor(sum, 16, 64);
    sum += __shfl_xor(sum, 32, 64);
    lrow = lrow * alpha + sum;
    mrow = mnew;

    // ---- rescale O by alpha (remap stats-lane -> C-layout rows) ----
    float al[4];
#pragma unroll
    for (int r = 0; r < 4; ++r) al[r] = __shfl(alpha, rsel + r, 64);
#pragma unroll
    for (int nt = 0; nt < 4; ++nt)
#pragma unroll
      for (int r = 0; r < 4; ++r) oacc[nt][r] *= al[r];

    // ---- V(st) resident (own: all but K(st+1)'s 4) + cross-wave barrier ----
    if (st < 7) asm volatile("s_waitcnt vmcnt(4)" ::: "memory");
    else        asm volatile("s_waitcnt vmcnt(0)" ::: "memory");
    barrier_raw();

    // ---- PV accumulate ----
#pragma unroll
    for (int k0 = 0; k0 < 4; ++k0) {
      bh8 pf = *(const bh8*)&sP[w * 16 + (lane & 15)][k0 * 32 + (lane >> 4) * 8];
#pragma unroll
      for (int nt = 0; nt < 4; ++nt) {
        bh8 vf = *(const bh8*)(sV + k0 * 2048 + (nt * 16 + (lane & 15)) * 32 + ksel);
        oacc[nt] = __builtin_amdgcn_mfma_f32_16x16x32_bf16(pf, vf, oacc[nt], 0, 0, 0);
      }
    }

    // ---- drain K(st+1) (issued a full tile ago — free) + barrier:
    //      guarantees cross-wave K residency for QK(st+1) and WAR safety
    //      for next tile's K/V DMA writes ----
    asm volatile("s_waitcnt vmcnt(0)" ::: "memory");
    barrier_raw();
  }

  float rl[4];
#pragma unroll
  for (int r = 0; r < 4; ++r) rl[r] = 1.0f / __shfl(lrow, rsel + r, 64);
  size_t ob = (size_t)b * 1048576;
#pragma unroll
  for (int nt = 0; nt < 4; ++nt) {
    int j = nt * 16 + (lane & 15);
    int t0 = qbase + w * 16 + rsel;
#pragma unroll
    for (int r = 0; r < 4; ++r)
      AO[ob + (size_t)(t0 + r) * 1024 + j0 + j] = f2bf(oacc[nt][r] * rl[r]);
  }
}

// ---------------------------------------------------------------------------
// Final projection: out[r][o] = sum_m A[r][m] * Wo[o][m] + bo[o]   (f32 out)
// ---------------------------------------------------------------------------
__global__ __launch_bounds__(256) void gemm_bt(
    const short* __restrict__ A, const short* __restrict__ Bm,
    float* __restrict__ out, const float* __restrict__ bias) {
  __shared__ short sA[4096];
  __shared__ short sB[4096];
  int tid = threadIdx.x, lane = tid & 63, w = tid >> 6;
  int mbase = blockIdx.x * 128, nbase = blockIdx.y * 128;
  int colsh = (lane & 3) * 8;
  int ldsoff[2]; const short* ap[2]; const short* bp[2];
#pragma unroll
  for (int i = 0; i < 2; ++i) {
    int row = 32 * w + 16 * i + (lane >> 2);
    ldsoff[i] = (2 * w + i) * 512 + lane * 8;
    ap[i] = A + (size_t)(mbase + row) * 1024 + colsh;
    bp[i] = Bm + (size_t)(nbase + row) * 1024 + colsh;
  }
  f32x4 acc[4][4] = {};
  int wm = (w >> 1) * 64, wn = (w & 1) * 64;
  for (int kt = 0; kt < 1024; kt += 32) {
#pragma unroll
    for (int i = 0; i < 2; ++i) {
      g2l16(ap[i] + kt, sA + ldsoff[i]);
      g2l16(bp[i] + kt, sB + ldsoff[i]);
    }
    __syncthreads();
    bh8 af[4], bfr[4];
#pragma unroll
    for (int mt = 0; mt < 4; ++mt)
      af[mt] = *(const bh8*)&sA[(wm + mt * 16 + (lane & 15)) * 32 + (lane >> 4) * 8];
#pragma unroll
    for (int nt = 0; nt < 4; ++nt)
      bfr[nt] = *(const bh8*)&sB[(wn + nt * 16 + (lane & 15)) * 32 + (lane >> 4) * 8];
#pragma unroll
    for (int mt = 0; mt < 4; ++mt)
#pragma unroll
      for (int nt = 0; nt < 4; ++nt)
        acc[mt][nt] = __builtin_amdgcn_mfma_f32_16x16x32_bf16(af[mt], bfr[nt], acc[mt][nt], 0, 0, 0);
    __syncthreads();
  }
#pragma unroll
  for (int mt = 0; mt < 4; ++mt) {
#pragma unroll
    for (int nt = 0; nt < 4; ++nt) {
      int m0 = mbase + wm + mt * 16 + ((lane >> 4) << 2);
      int n = nbase + wn + nt * 16 + (lane & 15);
      float bv = bias[n];
#pragma unroll
      for (int r = 0; r < 4; ++r)
        out[(size_t)(m0 + r) * 1024 + n] = acc[mt][nt][r] + bv;
    }
  }
}

// ---------------------------------------------------------------------------
extern "C" void kernel_launch(void* const* d_in, const int* in_sizes, int n_in,
                              void* d_out, int out_size, void* d_ws, size_t ws_size,
                              hipStream_t stream) {
  (void)in_sizes; (void)n_in; (void)out_size;
  const float* q    = (const float*)d_in[0];
  const float* k    = (const float*)d_in[1];
  const float* v    = (const float*)d_in[2];
  const float* Wq   = (const float*)d_in[3];
  const float* bq   = (const float*)d_in[4];
  const float* Wk   = (const float*)d_in[5];
  const float* bk   = (const float*)d_in[6];
  const float* Wv   = (const float*)d_in[7];
  const float* bv   = (const float*)d_in[8];
  const float* Wo   = (const float*)d_in[9];
  const float* bo   = (const float*)d_in[10];
  const int*   mask = (const int*)d_in[11];
  float* out = (float*)d_out;
  char* ws = (char*)d_ws;

  const size_t XPE = 1156ull * 1024 * 8;      // padded tensor elems (9,469,952)
  const size_t XPB = XPE * 2;                 // 18,939,904 B
  const size_t WPE = 9ull * 1048576;          // Wp elems
  short* xPq = (short*)ws;
  short* xPk = xPq + XPE;
  short* xPv = xPk + XPE;
  short* WpQ = (short*)(ws + 3 * XPB);
  short* WpK = WpQ + WPE;
  short* WpV = WpK + WPE;
  char* p2 = ws + 3 * XPB + 3 * WPE * 2;      // 113,442,816

  bool fused = ws_size >= 167000000ull;
  short *cQ, *cK, *cVT, *WoB, *AO; unsigned* Mpk;
  if (fused) {
    cQ  = (short*)(p2);
    cK  = (short*)(p2 + 16777216);
    cVT = (short*)(p2 + 33554432);
    WoB = (short*)(p2 + 50331648);
    Mpk = (unsigned*)(p2 + 52428800);
    AO  = xPq;                                 // dead after conv
  } else {
    cQ  = (short*)(p2);
    WoB = (short*)(p2 + 16777216);
    Mpk = (unsigned*)(p2 + 18874368);
    cK  = xPq;   // sequential: xPq dead after conv Q
    cVT = xPk;   // xPk dead after conv K
    AO  = xPv;   // xPv dead after conv V
  }

  zero_halo<<<dim3(66, 24), dim3(256), 0, stream>>>(xPq);
  transpose3<<<dim3(16, 16, 24), dim3(256), 0, stream>>>(q, k, v, xPq, xPk, xPv);
  wperm3<<<dim3(4096, 3), dim3(256), 0, stream>>>(Wq, Wk, Wv, WpQ, WpK, WpV);
  cvt_bf<<<dim3(1024), dim3(256), 0, stream>>>(Wo, WoB);
  mask_pack<<<dim3(1024), dim3(256), 0, stream>>>(mask, Mpk);
  if (fused) {
    conv_gemm_td<<<dim3(4, 8, 24), dim3(512), 0, stream>>>(
        WpQ, WpK, WpV, xPq, xPk, xPv, cQ, cK, cVT, bq, bk, bv, -1);
  } else {
    conv_gemm_td<<<dim3(4, 8, 8), dim3(512), 0, stream>>>(
        WpQ, WpK, WpV, xPq, xPk, xPv, cQ, cK, cVT, bq, bk, bv, 0);
    conv_gemm_td<<<dim3(4, 8, 8), dim3(512), 0, stream>>>(
        WpQ, WpK, WpV, xPq, xPk, xPv, cQ, cK, cVT, bq, bk, bv, 1);
    conv_gemm_td<<<dim3(4, 8, 8), dim3(512), 0, stream>>>(
        WpQ, WpK, WpV, xPq, xPk, xPv, cQ, cK, cVT, bq, bk, bv, 2);
  }
  attn<<<dim3(16, 16, 8), dim3(256), 0, stream>>>(cQ, cK, cVT, Mpk, AO);
  gemm_bt<<<dim3(64, 8), dim3(256), 0, stream>>>(AO, WoB, out, bo);
}